// Round 12
// baseline (63717.450 us; speedup 1.0000x reference)
//
#include <hip/hip_runtime.h>
#include <hip/hip_bf16.h>

typedef unsigned int u32;
typedef unsigned short u16;
typedef unsigned long long u64;
using half2_t = __attribute__((ext_vector_type(2))) _Float16;
using half8   = __attribute__((ext_vector_type(8))) _Float16;
using f32x4   = __attribute__((ext_vector_type(4))) float;
using u32x4   = __attribute__((ext_vector_type(4))) u32;

// Problem dims
#define TT 16384
#define HDIM 2048
#define N3H 6144
#define ODIM 1000

// Workspace layout (bytes). Total = 318,785,536 (~304 MB)
#define WS_WPACK 0ull                 // 25,165,824  : W_hh packed f16 pairs
#define WS_PROG  25165824ull          // 512         : progress counters [128] u32
#define WS_IG    117440512ull         // 201,326,592 : igates f16 [T][6144]
#define WS_PAIR  318767104ull         // 16,384      : h publish {tag16|f16} [2][2048] u32
#define WS_NEED  318785536ull

#if __has_builtin(__builtin_amdgcn_fdot2)
__device__ __forceinline__ float fdot2u(u32 a, u32 b, float c) {
  return __builtin_amdgcn_fdot2(__builtin_bit_cast(half2_t, a),
                                __builtin_bit_cast(half2_t, b), c, false);
}
#else
__device__ __forceinline__ float fdot2u(u32 a, u32 b, float c) {
  half2_t x = __builtin_bit_cast(half2_t, a), y = __builtin_bit_cast(half2_t, b);
  return c + (float)x[0] * (float)y[0] + (float)x[1] * (float)y[1];
}
#endif

// Coherent coalesced 16B load: sc0+sc1 -> served at the device coherence
// point; each dword individually atomic (all the in-band tag scheme needs).
__device__ __forceinline__ u32x4 poll_load16(const u32* p) {
  u32x4 r;
  asm volatile("global_load_dwordx4 %0, %1, off sc0 sc1\n\ts_waitcnt vmcnt(0)"
               : "=&v"(r) : "v"(p));
  return r;
}
// Coherent dword load at the CP.
__device__ __forceinline__ u32 cload4_cp(const u32* p) {
  u32 r;
  asm volatile("global_load_dword %0, %1, off sc0 sc1\n\ts_waitcnt vmcnt(0)"
               : "=&v"(r) : "v"(p));
  return r;
}
// Three coherent ushort loads, one RTT (single vmcnt drain). Forced placement:
// issued exactly here, drained here (R11 showed cacheable/sinkable loads lose).
__device__ __forceinline__ void ld3_f16_cp(const _Float16* p0, const _Float16* p1,
                                           const _Float16* p2, float& a, float& b, float& c) {
  u32 ra, rb, rc;
  asm volatile("global_load_ushort %0, %3, off sc0 sc1\n\t"
               "global_load_ushort %1, %4, off sc0 sc1\n\t"
               "global_load_ushort %2, %5, off sc0 sc1\n\t"
               "s_waitcnt vmcnt(0)"
               : "=&v"(ra), "=&v"(rb), "=&v"(rc)
               : "v"(p0), "v"(p1), "v"(p2));
  a = (float)__builtin_bit_cast(_Float16, (u16)ra);
  b = (float)__builtin_bit_cast(_Float16, (u16)rb);
  c = (float)__builtin_bit_cast(_Float16, (u16)rc);
}
// Coherent 2-byte store at the CP (write-through).
__device__ __forceinline__ void st2_cp(_Float16* p, _Float16 v) {
  u32 u = (u32)__builtin_bit_cast(u16, v);
  asm volatile("global_store_short %0, %1, off sc0 sc1" :: "v"(p), "v"(u) : "memory");
}
// Coherent 16B store at the CP; each dword individually atomic.
__device__ __forceinline__ void st16_cp(u32* p, u32x4 v) {
  asm volatile("global_store_dwordx4 %0, %1, off sc0 sc1" :: "v"(p), "v"(v) : "memory");
}

// ---------------- zero helpers (every launch: clears stale tags/counters) ----
__global__ void k_zero(u32* p) {
  p[blockIdx.x * 256 + threadIdx.x] = 0u;  // pair: 4096 dwords
}
__global__ void k_zero_n(u32* p, int n) {
  int i = blockIdx.x * 256 + threadIdx.x;
  if (i < n) p[i] = 0u;
}

// ---------------- pack W_hh into per-(hrow,wave,lane) f16-pair layout --------
// (verbatim R3/R9) dword idx = hrow*3072 + c*256 + lane*4 + q ; dl=c*4+q
// g=dl/16 ; m=dl%16 ; value = (W_hh[g*2048+hrow][2*(lane*16+m)], ...+1)
__global__ __launch_bounds__(256) void k_pack(const float* __restrict__ whh,
                                              u32* __restrict__ outp) {
  u32 idx = blockIdx.x * 256 + threadIdx.x;  // < 6,291,456
  u32 hrow = idx / 3072;
  u32 rem = idx - hrow * 3072;
  u32 c = rem >> 8;
  u32 lane = (rem >> 2) & 63;
  u32 q = rem & 3;
  u32 dl = c * 4 + q;
  u32 g = dl >> 4;
  u32 m = dl & 15;
  u32 kp = lane * 16 + m;
  const float* src = whh + (size_t)(g * 2048 + hrow) * 2048 + 2 * kp;
  half2_t p;
  p[0] = (_Float16)src[0];
  p[1] = (_Float16)src[1];
  outp[idx] = __builtin_bit_cast(u32, p);
}

__device__ __forceinline__ u32 packf16(float a, float b) {
  half2_t p;
  p[0] = (_Float16)a;
  p[1] = (_Float16)b;
  return __builtin_bit_cast(u32, p);
}

// ---------------- fused coop kernel: 256 WGs x 512 thr -----------------------
// WG 0..63   : GRU scan. Wave v owns rows r0 = wg*32 + v*4 .. r0+3 (4/wave).
//   Weights in registers (4 x 48 f16-pair dwords). Lane l covers k slice
//   [32l, 32l+32). Publish: ONE dwordx4 sc0sc1 store per wave (4 x {tag|f16}).
//   Consumer poll + LDS exchange verbatim R10 (tid polls pair + 4*tid).
// WG 64..255 : igates GEMM helpers (write igates sc0sc1; drain; bump prog).
//   Scan gates igate reads on prog[mblock]==48, reads them via forced CP loads.
__global__ __launch_bounds__(512) void k_fused(const uint4* __restrict__ wpack,
                                               const _Float16* __restrict__ ig,
                                               const float* __restrict__ bias_n,
                                               u32* pair,
                                               const float* __restrict__ X,
                                               const float* __restrict__ Wih,
                                               const float* __restrict__ bias,
                                               u32* prog) {
  __shared__ __align__(16) u32 smem[4096];  // 16KB: scan uses 1280, gemm 4096
  const int tid = threadIdx.x;

  if (blockIdx.x < 64) {
    // ======================= SCAN ==========================================
    u32* lds_h = smem;  // 1024 f16-pair dwords + pad 4/16
    const int l = tid & 63, v = tid >> 6;
    const int wg = blockIdx.x;
    const int r0 = wg * 32 + v * 4;
    const int my_row = r0 + (l & 3);

    u32 wdw[4][48];  // all indices static after unroll (rule #20)
    {
      const uint4* wp0 = wpack + (size_t)r0 * 768 + l;
#pragma unroll
      for (int j = 0; j < 4; ++j) {
        const uint4* wpj = wp0 + j * 768;
#pragma unroll
        for (int c = 0; c < 12; ++c) {
          uint4 a = wpj[(size_t)c * 64];
          wdw[j][c * 4] = a.x; wdw[j][c * 4 + 1] = a.y;
          wdw[j][c * 4 + 2] = a.z; wdw[j][c * 4 + 3] = a.w;
        }
      }
    }
    const float bn = bias_n[my_row];
    float hm = 0.f;  // fp32 master state for my_row (valid in lanes 0..3)
    u32 hreg[16];
#pragma unroll
    for (int m = 0; m < 16; ++m) hreg[m] = 0;  // h(0) = 0

    int ready_blk = 0;
    {  // gate igates m-block 0 (one broadcast CP dword per round)
      for (;;) {
        u32 c = cload4_cp(prog);
        if (c >= 48u) break;
        __builtin_amdgcn_s_sleep(8);
      }
      ready_blk = 1;
    }
    float ig0, ig1, ig2;
    ld3_f16_cp(ig + my_row, ig + 2048 + my_row, ig + 4096 + my_row, ig0, ig1, ig2);

    for (int t = 0; t < TT; ++t) {
      float igr = ig0, igz = ig1, ign = ig2;
      float s[12];
#pragma unroll
      for (int i = 0; i < 12; ++i) s[i] = 0.f;
#pragma unroll
      for (int m = 0; m < 16; ++m) {
        u32 h = hreg[m];
#pragma unroll
        for (int j = 0; j < 4; ++j) {
          s[3 * j + 0] = fdot2u(wdw[j][m],      h, s[3 * j + 0]);
          s[3 * j + 1] = fdot2u(wdw[j][16 + m], h, s[3 * j + 1]);
          s[3 * j + 2] = fdot2u(wdw[j][32 + m], h, s[3 * j + 2]);
        }
      }
#pragma unroll
      for (int off = 1; off < 64; off <<= 1) {
#pragma unroll
        for (int i = 0; i < 12; ++i) s[i] += __shfl_xor(s[i], off, 64);
      }
      u32* pdst = pair + (((t + 1) & 1) << 11);
      u32 pk = 0;
      if (l < 4) {  // lane j computes row r0+j (static select, no dyn index)
        float sr = l == 0 ? s[0] : l == 1 ? s[3] : l == 2 ? s[6] : s[9];
        float sz = l == 0 ? s[1] : l == 1 ? s[4] : l == 2 ? s[7] : s[10];
        float sn = l == 0 ? s[2] : l == 1 ? s[5] : l == 2 ? s[8] : s[11];
        float r = 1.f / (1.f + __expf(-(igr + sr)));
        float z = 1.f / (1.f + __expf(-(igz + sz)));
        float nx = ign + r * (sn + bn);
        float e = __expf(-2.f * nx);
        float n = (1.f - e) / (1.f + e);
        hm = n + z * (hm - n);
        pk = ((u32)(t + 1) << 16) | (u32)__builtin_bit_cast(u16, (_Float16)hm);
      }
      u32 pk1 = __shfl(pk, 1, 64);
      u32 pk2 = __shfl(pk, 2, 64);
      u32 pk3 = __shfl(pk, 3, 64);
      if (l == 0) {
        u32x4 pv;
        pv[0] = pk; pv[1] = pk1; pv[2] = pk2; pv[3] = pk3;
        st16_cp(pdst + r0, pv);  // r0 is 4-dword aligned
      }
      if (t == TT - 1) break;
      {  // gate + prefetch next igates row (forced CP loads; hide under poll)
        int nb = (t + 1) >> 7;
        if (nb >= ready_blk) {
          const u32* pb = prog + nb;
          for (;;) {
            u32 c = cload4_cp(pb);
            if (c >= 48u) break;
            __builtin_amdgcn_s_sleep(8);
          }
          ready_blk = nb + 1;
        }
        const _Float16* igp = ig + (size_t)(t + 1) * N3H;
        ld3_f16_cp(igp + my_row, igp + 2048 + my_row, igp + 4096 + my_row, ig0, ig1, ig2);
      }
      // poll own 4 rows (verbatim R3/R9/R10)
      const u32 tgt = (u32)(t + 1) << 16;
      const u32* pp = pdst + 4 * tid;
      __builtin_amdgcn_s_sleep(2);
      u32x4 d;
      for (;;) {
        d = poll_load16(pp);
        u32 bad = ((d[0] ^ tgt) | (d[1] ^ tgt) | (d[2] ^ tgt) | (d[3] ^ tgt)) & 0xFFFF0000u;
        if (!bad) break;
        __builtin_amdgcn_s_sleep(2);
      }
      __syncthreads();  // all local waves done reading lds_h of prev step
      u32 p0 = (d[0] & 0xFFFFu) | (d[1] << 16);
      u32 p1 = (d[2] & 0xFFFFu) | (d[3] << 16);
      u32* dst = lds_h + 2 * tid + ((tid >> 3) << 2);  // pad 4 dwords per 16
      dst[0] = p0;
      dst[1] = p1;
      __syncthreads();
#pragma unroll
      for (int i = 0; i < 4; ++i) {
        uint4 vv = *(const uint4*)(lds_h + l * 20 + i * 4);
        hreg[i * 4] = vv.x; hreg[i * 4 + 1] = vv.y; hreg[i * 4 + 2] = vv.z; hreg[i * 4 + 3] = vv.w;
      }
    }
  } else {
    // ======================= GEMM HELPERS ===================================
    _Float16* As = (_Float16*)smem;           // [128][32] f16 = 8KB
    _Float16* Bs = (_Float16*)(smem + 2048);  // [128][32] f16 = 8KB
    const int hid = blockIdx.x - 64;          // 0..191
    const int l = tid & 63, w = tid >> 6;
    const int wr = w >> 2, wc = w & 3;        // 2x4 wave grid
    const int srow = tid >> 2;                // 0..127
    const int scol = (tid & 3) << 3;          // 0,8,16,24

    for (int tile = hid; tile < 6144; tile += 192) {
      const int mb = tile / 48, nb = tile - mb * 48;
      const int m0 = mb * 128, n0 = nb * 128;
      f32x4 acc[4][2] = {};

      for (int k0 = 0; k0 < HDIM; k0 += 32) {
        __syncthreads();
        const float* ap = X + (size_t)(m0 + srow) * HDIM + k0 + scol;
        const float* bp = Wih + (size_t)(n0 + srow) * HDIM + k0 + scol;
        float4 aL = *(const float4*)ap, aH = *(const float4*)(ap + 4);
        float4 bL = *(const float4*)bp, bH = *(const float4*)(bp + 4);
        uint4 av4 = make_uint4(packf16(aL.x, aL.y), packf16(aL.z, aL.w),
                               packf16(aH.x, aH.y), packf16(aH.z, aH.w));
        uint4 bv4 = make_uint4(packf16(bL.x, bL.y), packf16(bL.z, bL.w),
                               packf16(bH.x, bH.y), packf16(bH.z, bH.w));
        *(uint4*)(As + srow * 32 + scol) = av4;
        *(uint4*)(Bs + srow * 32 + scol) = bv4;
        __syncthreads();
        half8 av[4], bv[2];
#pragma unroll
        for (int mi = 0; mi < 4; ++mi)
          av[mi] = *(const half8*)(As + (wr * 64 + mi * 16 + (l & 15)) * 32 + (l >> 4) * 8);
#pragma unroll
        for (int ni = 0; ni < 2; ++ni)
          bv[ni] = *(const half8*)(Bs + (wc * 32 + ni * 16 + (l & 15)) * 32 + (l >> 4) * 8);
#pragma unroll
        for (int mi = 0; mi < 4; ++mi)
#pragma unroll
          for (int ni = 0; ni < 2; ++ni)
            acc[mi][ni] = __builtin_amdgcn_mfma_f32_16x16x32_f16(av[mi], bv[ni], acc[mi][ni], 0, 0, 0);
      }
      _Float16* Cout = (_Float16*)ig;
#pragma unroll
      for (int ni = 0; ni < 2; ++ni) {
        int col = n0 + wc * 32 + ni * 16 + (l & 15);
        float bb = bias[col];
#pragma unroll
        for (int mi = 0; mi < 4; ++mi) {
          int rbase = m0 + wr * 64 + mi * 16 + (l >> 4) * 4;
#pragma unroll
          for (int r = 0; r < 4; ++r)
            st2_cp(Cout + (size_t)(rbase + r) * N3H + col,
                   (_Float16)(acc[mi][ni][r] + bb));
        }
      }
      asm volatile("s_waitcnt vmcnt(0)" ::: "memory");  // data at CP
      __syncthreads();                                   // all threads drained
      if (tid == 0)
        __hip_atomic_fetch_add(prog + mb, 1u, __ATOMIC_RELAXED,
                               __HIP_MEMORY_SCOPE_AGENT);
    }
  }
}

// ---------------- final projection: out = w_out @ h_final + b_out + b_extra --
// h_final is in pair buffer 0 (TT even), f16 in low 16 bits of each dword.
__global__ __launch_bounds__(256) void k_out(const float* __restrict__ wout,
                                             const float* __restrict__ bout,
                                             const float* __restrict__ bextra,
                                             const u32* __restrict__ hp,
                                             float* __restrict__ out) {
  const int l = threadIdx.x & 63;
  const int o = blockIdx.x * 4 + (threadIdx.x >> 6);
  if (o >= ODIM) return;
  const float* wr = wout + (size_t)o * HDIM;
  float acc = 0.f;
#pragma unroll
  for (int i = 0; i < 8; ++i) {
    int k4 = i * 256 + l * 4;
    uint4 hd = *(const uint4*)(hp + k4);
    float4 wv = *(const float4*)(wr + k4);
    acc += wv.x * (float)__builtin_bit_cast(_Float16, (u16)(hd.x & 0xFFFFu));
    acc += wv.y * (float)__builtin_bit_cast(_Float16, (u16)(hd.y & 0xFFFFu));
    acc += wv.z * (float)__builtin_bit_cast(_Float16, (u16)(hd.z & 0xFFFFu));
    acc += wv.w * (float)__builtin_bit_cast(_Float16, (u16)(hd.w & 0xFFFFu));
  }
#pragma unroll
  for (int off = 1; off < 64; off <<= 1) acc += __shfl_xor(acc, off, 64);
  if (l == 0) out[o] = acc + bout[o] + bextra[o];
}

// sentinel if workspace too small: absmax ~= 1e6 + ws_size_in_MB (debug channel)
__global__ void k_dbg(float* out, float v) {
  int i = blockIdx.x * 256 + threadIdx.x;
  if (i < ODIM) out[i] = v;
}

extern "C" void kernel_launch(void* const* d_in, const int* in_sizes, int n_in,
                              void* d_out, int out_size, void* d_ws, size_t ws_size,
                              hipStream_t stream) {
  const float* x      = (const float*)d_in[0];
  const float* wih    = (const float*)d_in[1];
  const float* whh    = (const float*)d_in[2];
  const float* bias   = (const float*)d_in[3];
  const float* bias_n = (const float*)d_in[4];
  const float* wout   = (const float*)d_in[5];
  const float* bout   = (const float*)d_in[6];
  const float* bextra = (const float*)d_in[7];
  float* out = (float*)d_out;

  if (ws_size < WS_NEED) {
    k_dbg<<<4, 256, 0, stream>>>(out, 1.0e6f + (float)(ws_size / 1048576ull));
    return;
  }

  char* ws = (char*)d_ws;
  u32*      wpack = (u32*)(ws + WS_WPACK);
  u32*      prog  = (u32*)(ws + WS_PROG);
  _Float16* igb   = (_Float16*)(ws + WS_IG);
  u32*      pairb = (u32*)(ws + WS_PAIR);

  k_zero<<<16, 256, 0, stream>>>(pairb);
  k_zero_n<<<1, 256, 0, stream>>>(prog, 128);
  k_pack<<<24576, 256, 0, stream>>>(whh, wpack);

  const uint4* wpc = (const uint4*)wpack;
  const _Float16* igc = igb;
  void* kargs[] = {(void*)&wpc, (void*)&igc, (void*)&bias_n, (void*)&pairb,
                   (void*)&x, (void*)&wih, (void*)&bias, (void*)&prog};
  hipLaunchCooperativeKernel(k_fused, dim3(256), dim3(512), kargs, 0, stream);

  k_out<<<250, 256, 0, stream>>>(wout, bout, bextra, pairb, out);
}

// Round 13
// 57882.367 us; speedup vs baseline: 1.1008x; 1.1008x over previous
//
#include <hip/hip_runtime.h>
#include <hip/hip_bf16.h>

typedef unsigned int u32;
typedef unsigned short u16;
typedef unsigned long long u64;
using half2_t = __attribute__((ext_vector_type(2))) _Float16;
using half8   = __attribute__((ext_vector_type(8))) _Float16;
using f32x4   = __attribute__((ext_vector_type(4))) float;
using u32x4   = __attribute__((ext_vector_type(4))) u32;

// Problem dims
#define TT 16384
#define HDIM 2048
#define N3H 6144
#define ODIM 1000

// Workspace layout (bytes). Total = 318,785,536 (~304 MB)
#define WS_WPACK 0ull                 // 25,165,824  : W_hh packed f16 pairs
#define WS_PROG  25165824ull          // 512         : progress counters [128] u32
#define WS_IG    117440512ull         // 201,326,592 : igates f16 [T][6144]
#define WS_PAIR  318767104ull         // 16,384      : h publish {tag16|f16} [2][2048] u32
#define WS_NEED  318785536ull

#if __has_builtin(__builtin_amdgcn_fdot2)
__device__ __forceinline__ float fdot2u(u32 a, u32 b, float c) {
  return __builtin_amdgcn_fdot2(__builtin_bit_cast(half2_t, a),
                                __builtin_bit_cast(half2_t, b), c, false);
}
#else
__device__ __forceinline__ float fdot2u(u32 a, u32 b, float c) {
  half2_t x = __builtin_bit_cast(half2_t, a), y = __builtin_bit_cast(half2_t, b);
  return c + (float)x[0] * (float)y[0] + (float)x[1] * (float)y[1];
}
#endif

// Coherent coalesced 16B load: sc0+sc1 -> served at the device coherence
// point; each dword individually atomic (all the in-band tag scheme needs).
__device__ __forceinline__ u32x4 poll_load16(const u32* p) {
  u32x4 r;
  asm volatile("global_load_dwordx4 %0, %1, off sc0 sc1\n\ts_waitcnt vmcnt(0)"
               : "=&v"(r) : "v"(p));
  return r;
}
// Coherent dword load at the CP.
__device__ __forceinline__ u32 cload4_cp(const u32* p) {
  u32 r;
  asm volatile("global_load_dword %0, %1, off sc0 sc1\n\ts_waitcnt vmcnt(0)"
               : "=&v"(r) : "v"(p));
  return r;
}
// Three coherent ushort loads with drain (used once, before the main loop).
__device__ __forceinline__ void ld3_f16_cp(const _Float16* p0, const _Float16* p1,
                                           const _Float16* p2, float& a, float& b, float& c) {
  u32 ra, rb, rc;
  asm volatile("global_load_ushort %0, %3, off sc0 sc1\n\t"
               "global_load_ushort %1, %4, off sc0 sc1\n\t"
               "global_load_ushort %2, %5, off sc0 sc1\n\t"
               "s_waitcnt vmcnt(0)"
               : "=&v"(ra), "=&v"(rb), "=&v"(rc)
               : "v"(p0), "v"(p1), "v"(p2));
  a = (float)__builtin_bit_cast(_Float16, (u16)ra);
  b = (float)__builtin_bit_cast(_Float16, (u16)rb);
  c = (float)__builtin_bit_cast(_Float16, (u16)rc);
}
// ISSUE-ONLY variant: 3 CP ushort loads, NO drain. The registers become valid
// after any subsequent s_waitcnt vmcnt(0) -- the h-poll loop (which always
// executes >=1 poll_load16) provides it, hiding this RTT under the poll wait.
__device__ __forceinline__ void ld3_f16_issue(const _Float16* p0, const _Float16* p1,
                                              const _Float16* p2, u32& ra, u32& rb, u32& rc) {
  asm volatile("global_load_ushort %0, %3, off sc0 sc1\n\t"
               "global_load_ushort %1, %4, off sc0 sc1\n\t"
               "global_load_ushort %2, %5, off sc0 sc1"
               : "=&v"(ra), "=&v"(rb), "=&v"(rc)
               : "v"(p0), "v"(p1), "v"(p2));
}
// Coherent 2-byte store at the CP (write-through).
__device__ __forceinline__ void st2_cp(_Float16* p, _Float16 v) {
  u32 u = (u32)__builtin_bit_cast(u16, v);
  asm volatile("global_store_short %0, %1, off sc0 sc1" :: "v"(p), "v"(u) : "memory");
}

// ---------------- zero helpers (every launch: clears stale tags/counters) ----
__global__ void k_zero(u32* p) {
  p[blockIdx.x * 256 + threadIdx.x] = 0u;  // pair: 4096 dwords
}
__global__ void k_zero_n(u32* p, int n) {
  int i = blockIdx.x * 256 + threadIdx.x;
  if (i < n) p[i] = 0u;
}

// ---------------- pack W_hh into per-(hrow,wave,lane) f16-pair layout --------
// (verbatim R3/R9) dword idx = hrow*3072 + c*256 + lane*4 + q ; dl=c*4+q
// g=dl/16 ; m=dl%16 ; value = (W_hh[g*2048+hrow][2*(lane*16+m)], ...+1)
__global__ __launch_bounds__(256) void k_pack(const float* __restrict__ whh,
                                              u32* __restrict__ outp) {
  u32 idx = blockIdx.x * 256 + threadIdx.x;  // < 6,291,456
  u32 hrow = idx / 3072;
  u32 rem = idx - hrow * 3072;
  u32 c = rem >> 8;
  u32 lane = (rem >> 2) & 63;
  u32 q = rem & 3;
  u32 dl = c * 4 + q;
  u32 g = dl >> 4;
  u32 m = dl & 15;
  u32 kp = lane * 16 + m;
  const float* src = whh + (size_t)(g * 2048 + hrow) * 2048 + 2 * kp;
  half2_t p;
  p[0] = (_Float16)src[0];
  p[1] = (_Float16)src[1];
  outp[idx] = __builtin_bit_cast(u32, p);
}

__device__ __forceinline__ u32 packf16(float a, float b) {
  half2_t p;
  p[0] = (_Float16)a;
  p[1] = (_Float16)b;
  return __builtin_bit_cast(u32, p);
}

// ---------------- fused coop kernel: 256 WGs x 512 thr -----------------------
// WG 0..127  : GRU scan (R9/R10 core), rows r0 = wg*16 + 2v per wave v.
// WG 128..255: igates GEMM helpers (write igates sc0sc1; drain; bump prog).
// R13 change vs R10 (single, isolated): the per-step igate prefetch no longer
// drains vmcnt before the h-poll; its CP RTT hides under the poll's own
// vmcnt(0). Consume point (empty asm tie) sits after the poll loop.
__global__ __launch_bounds__(512) void k_fused(const uint4* __restrict__ wpack,
                                               const _Float16* __restrict__ ig,
                                               const float* __restrict__ bias_n,
                                               u32* pair,
                                               const float* __restrict__ X,
                                               const float* __restrict__ Wih,
                                               const float* __restrict__ bias,
                                               u32* prog) {
  __shared__ __align__(16) u32 smem[4096];  // 16KB: scan uses 1280, gemm 4096
  const int tid = threadIdx.x;

  if (blockIdx.x < 128) {
    // ======================= SCAN ==========================================
    u32* lds_h = smem;  // 1024 f16-pair dwords + pad 4/16
    const int l = tid & 63, v = tid >> 6;
    const int wg = blockIdx.x;
    const int r0 = wg * 16 + v * 2;
    const int my_row = r0 + (l & 1);

    u32 wdwA[48], wdwB[48];
    {
      const uint4* wpA = wpack + (size_t)r0 * 768 + l;
      const uint4* wpB = wpA + 768;  // row r0+1
#pragma unroll
      for (int c = 0; c < 12; ++c) {
        uint4 a = wpA[(size_t)c * 64];
        wdwA[c * 4] = a.x; wdwA[c * 4 + 1] = a.y; wdwA[c * 4 + 2] = a.z; wdwA[c * 4 + 3] = a.w;
      }
#pragma unroll
      for (int c = 0; c < 12; ++c) {
        uint4 b = wpB[(size_t)c * 64];
        wdwB[c * 4] = b.x; wdwB[c * 4 + 1] = b.y; wdwB[c * 4 + 2] = b.z; wdwB[c * 4 + 3] = b.w;
      }
    }
    const float bn = bias_n[my_row];
    float hm = 0.f;  // fp32 master state for my_row (valid in lanes 0,1)
    u32 hreg[16];
#pragma unroll
    for (int m = 0; m < 16; ++m) hreg[m] = 0;  // h(0) = 0

    int ready_blk = 0;
    {  // gate igates m-block 0 (one broadcast CP dword per round)
      for (;;) {
        u32 c = cload4_cp(prog);
        if (c >= 48u) break;
        __builtin_amdgcn_s_sleep(8);
      }
      ready_blk = 1;
    }
    float ig0, ig1, ig2;
    ld3_f16_cp(ig + my_row, ig + 2048 + my_row, ig + 4096 + my_row, ig0, ig1, ig2);

    for (int t = 0; t < TT; ++t) {
      float igr = ig0, igz = ig1, ign = ig2;
      float a0 = 0.f, a1 = 0.f, a2 = 0.f, a3 = 0.f, a4 = 0.f, a5 = 0.f;
      float b0 = 0.f, b1 = 0.f, b2 = 0.f, b3 = 0.f, b4 = 0.f, b5 = 0.f;
#pragma unroll
      for (int m = 0; m < 16; m += 2) {
        a0 = fdot2u(wdwA[m],          hreg[m],     a0);
        b0 = fdot2u(wdwA[m + 1],      hreg[m + 1], b0);
        a1 = fdot2u(wdwA[16 + m],     hreg[m],     a1);
        b1 = fdot2u(wdwA[16 + m + 1], hreg[m + 1], b1);
        a2 = fdot2u(wdwA[32 + m],     hreg[m],     a2);
        b2 = fdot2u(wdwA[32 + m + 1], hreg[m + 1], b2);
        a3 = fdot2u(wdwB[m],          hreg[m],     a3);
        b3 = fdot2u(wdwB[m + 1],      hreg[m + 1], b3);
        a4 = fdot2u(wdwB[16 + m],     hreg[m],     a4);
        b4 = fdot2u(wdwB[16 + m + 1], hreg[m + 1], b4);
        a5 = fdot2u(wdwB[32 + m],     hreg[m],     a5);
        b5 = fdot2u(wdwB[32 + m + 1], hreg[m + 1], b5);
      }
      float s0 = a0 + b0, s1 = a1 + b1, s2 = a2 + b2;
      float s3 = a3 + b3, s4 = a4 + b4, s5 = a5 + b5;
#pragma unroll
      for (int off = 1; off < 64; off <<= 1) {
        s0 += __shfl_xor(s0, off, 64);
        s1 += __shfl_xor(s1, off, 64);
        s2 += __shfl_xor(s2, off, 64);
        s3 += __shfl_xor(s3, off, 64);
        s4 += __shfl_xor(s4, off, 64);
        s5 += __shfl_xor(s5, off, 64);
      }
      u32* pdst = pair + (((t + 1) & 1) << 11);
      u32 pk = 0;
      if (l < 2) {
        float sr = l ? s3 : s0, sz = l ? s4 : s1, sn = l ? s5 : s2;
        float r = 1.f / (1.f + __expf(-(igr + sr)));
        float z = 1.f / (1.f + __expf(-(igz + sz)));
        float nx = ign + r * (sn + bn);
        float e = __expf(-2.f * nx);
        float n = (1.f - e) / (1.f + e);
        hm = n + z * (hm - n);
        pk = ((u32)(t + 1) << 16) | (u32)__builtin_bit_cast(u16, (_Float16)hm);
      }
      u32 pk1 = __shfl(pk, 1, 64);  // row r0+1's packed dword -> lane 0
      if (l == 0)
        __hip_atomic_store((u64*)(pdst + r0), (u64)pk | ((u64)pk1 << 32),
                           __ATOMIC_RELAXED, __HIP_MEMORY_SCOPE_AGENT);
      if (t == TT - 1) break;
      u32 ra, rb, rc;
      {  // gate (rare), then ISSUE next igate loads -- no drain here
        int nb = (t + 1) >> 7;
        if (nb >= ready_blk) {
          const u32* pb = prog + nb;
          for (;;) {
            u32 c = cload4_cp(pb);
            if (c >= 48u) break;
            __builtin_amdgcn_s_sleep(8);
          }
          ready_blk = nb + 1;
        }
        const _Float16* igp = ig + (size_t)(t + 1) * N3H;
        ld3_f16_issue(igp + my_row, igp + 2048 + my_row, igp + 4096 + my_row, ra, rb, rc);
      }
      // poll own 4 rows (verbatim R3/R9/R10); its vmcnt(0) also drains the
      // igate loads issued above.
      const u32 tgt = (u32)(t + 1) << 16;
      const u32* pp = pdst + 4 * tid;
      __builtin_amdgcn_s_sleep(2);
      u32x4 d;
      for (;;) {
        d = poll_load16(pp);
        u32 bad = ((d[0] ^ tgt) | (d[1] ^ tgt) | (d[2] ^ tgt) | (d[3] ^ tgt)) & 0xFFFF0000u;
        if (!bad) break;
        __builtin_amdgcn_s_sleep(2);
      }
      // consume point: vmcnt==0 here (poll executed >=1 round), regs valid.
      asm volatile("" : "+v"(ra), "+v"(rb), "+v"(rc));
      ig0 = (float)__builtin_bit_cast(_Float16, (u16)ra);
      ig1 = (float)__builtin_bit_cast(_Float16, (u16)rb);
      ig2 = (float)__builtin_bit_cast(_Float16, (u16)rc);
      __syncthreads();  // all local waves done reading lds_h of prev step
      u32 p0 = (d[0] & 0xFFFFu) | (d[1] << 16);
      u32 p1 = (d[2] & 0xFFFFu) | (d[3] << 16);
      u32* dst = lds_h + 2 * tid + ((tid >> 3) << 2);  // pad 4 dwords per 16
      dst[0] = p0;
      dst[1] = p1;
      __syncthreads();
#pragma unroll
      for (int i = 0; i < 4; ++i) {
        uint4 vv = *(const uint4*)(lds_h + l * 20 + i * 4);
        hreg[i * 4] = vv.x; hreg[i * 4 + 1] = vv.y; hreg[i * 4 + 2] = vv.z; hreg[i * 4 + 3] = vv.w;
      }
    }
  } else {
    // ======================= GEMM HELPERS ===================================
    _Float16* As = (_Float16*)smem;           // [128][32] f16 = 8KB
    _Float16* Bs = (_Float16*)(smem + 2048);  // [128][32] f16 = 8KB
    const int hid = blockIdx.x - 128;
    const int l = tid & 63, w = tid >> 6;
    const int wr = w >> 2, wc = w & 3;        // 2x4 wave grid
    const int srow = tid >> 2;                // 0..127
    const int scol = (tid & 3) << 3;          // 0,8,16,24

    for (int tile = hid; tile < 6144; tile += 128) {
      const int mb = tile / 48, nb = tile - mb * 48;
      const int m0 = mb * 128, n0 = nb * 128;
      f32x4 acc[4][2] = {};

      for (int k0 = 0; k0 < HDIM; k0 += 32) {
        __syncthreads();
        const float* ap = X + (size_t)(m0 + srow) * HDIM + k0 + scol;
        const float* bp = Wih + (size_t)(n0 + srow) * HDIM + k0 + scol;
        float4 aL = *(const float4*)ap, aH = *(const float4*)(ap + 4);
        float4 bL = *(const float4*)bp, bH = *(const float4*)(bp + 4);
        uint4 av4 = make_uint4(packf16(aL.x, aL.y), packf16(aL.z, aL.w),
                               packf16(aH.x, aH.y), packf16(aH.z, aH.w));
        uint4 bv4 = make_uint4(packf16(bL.x, bL.y), packf16(bL.z, bL.w),
                               packf16(bH.x, bH.y), packf16(bH.z, bH.w));
        *(uint4*)(As + srow * 32 + scol) = av4;
        *(uint4*)(Bs + srow * 32 + scol) = bv4;
        __syncthreads();
        half8 av[4], bv[2];
#pragma unroll
        for (int mi = 0; mi < 4; ++mi)
          av[mi] = *(const half8*)(As + (wr * 64 + mi * 16 + (l & 15)) * 32 + (l >> 4) * 8);
#pragma unroll
        for (int ni = 0; ni < 2; ++ni)
          bv[ni] = *(const half8*)(Bs + (wc * 32 + ni * 16 + (l & 15)) * 32 + (l >> 4) * 8);
#pragma unroll
        for (int mi = 0; mi < 4; ++mi)
#pragma unroll
          for (int ni = 0; ni < 2; ++ni)
            acc[mi][ni] = __builtin_amdgcn_mfma_f32_16x16x32_f16(av[mi], bv[ni], acc[mi][ni], 0, 0, 0);
      }
      _Float16* Cout = (_Float16*)ig;
#pragma unroll
      for (int ni = 0; ni < 2; ++ni) {
        int col = n0 + wc * 32 + ni * 16 + (l & 15);
        float bb = bias[col];
#pragma unroll
        for (int mi = 0; mi < 4; ++mi) {
          int rbase = m0 + wr * 64 + mi * 16 + (l >> 4) * 4;
#pragma unroll
          for (int r = 0; r < 4; ++r)
            st2_cp(Cout + (size_t)(rbase + r) * N3H + col,
                   (_Float16)(acc[mi][ni][r] + bb));
        }
      }
      asm volatile("s_waitcnt vmcnt(0)" ::: "memory");  // data at CP
      __syncthreads();                                   // all threads drained
      if (tid == 0)
        __hip_atomic_fetch_add(prog + mb, 1u, __ATOMIC_RELAXED,
                               __HIP_MEMORY_SCOPE_AGENT);
    }
  }
}

// ---------------- final projection: out = w_out @ h_final + b_out + b_extra --
// h_final is in pair buffer 0 (TT even), f16 in low 16 bits of each dword.
__global__ __launch_bounds__(256) void k_out(const float* __restrict__ wout,
                                             const float* __restrict__ bout,
                                             const float* __restrict__ bextra,
                                             const u32* __restrict__ hp,
                                             float* __restrict__ out) {
  const int l = threadIdx.x & 63;
  const int o = blockIdx.x * 4 + (threadIdx.x >> 6);
  if (o >= ODIM) return;
  const float* wr = wout + (size_t)o * HDIM;
  float acc = 0.f;
#pragma unroll
  for (int i = 0; i < 8; ++i) {
    int k4 = i * 256 + l * 4;
    uint4 hd = *(const uint4*)(hp + k4);
    float4 wv = *(const float4*)(wr + k4);
    acc += wv.x * (float)__builtin_bit_cast(_Float16, (u16)(hd.x & 0xFFFFu));
    acc += wv.y * (float)__builtin_bit_cast(_Float16, (u16)(hd.y & 0xFFFFu));
    acc += wv.z * (float)__builtin_bit_cast(_Float16, (u16)(hd.z & 0xFFFFu));
    acc += wv.w * (float)__builtin_bit_cast(_Float16, (u16)(hd.w & 0xFFFFu));
  }
#pragma unroll
  for (int off = 1; off < 64; off <<= 1) acc += __shfl_xor(acc, off, 64);
  if (l == 0) out[o] = acc + bout[o] + bextra[o];
}

// sentinel if workspace too small: absmax ~= 1e6 + ws_size_in_MB (debug channel)
__global__ void k_dbg(float* out, float v) {
  int i = blockIdx.x * 256 + threadIdx.x;
  if (i < ODIM) out[i] = v;
}

extern "C" void kernel_launch(void* const* d_in, const int* in_sizes, int n_in,
                              void* d_out, int out_size, void* d_ws, size_t ws_size,
                              hipStream_t stream) {
  const float* x      = (const float*)d_in[0];
  const float* wih    = (const float*)d_in[1];
  const float* whh    = (const float*)d_in[2];
  const float* bias   = (const float*)d_in[3];
  const float* bias_n = (const float*)d_in[4];
  const float* wout   = (const float*)d_in[5];
  const float* bout   = (const float*)d_in[6];
  const float* bextra = (const float*)d_in[7];
  float* out = (float*)d_out;

  if (ws_size < WS_NEED) {
    k_dbg<<<4, 256, 0, stream>>>(out, 1.0e6f + (float)(ws_size / 1048576ull));
    return;
  }

  char* ws = (char*)d_ws;
  u32*      wpack = (u32*)(ws + WS_WPACK);
  u32*      prog  = (u32*)(ws + WS_PROG);
  _Float16* igb   = (_Float16*)(ws + WS_IG);
  u32*      pairb = (u32*)(ws + WS_PAIR);

  k_zero<<<16, 256, 0, stream>>>(pairb);
  k_zero_n<<<1, 256, 0, stream>>>(prog, 128);
  k_pack<<<24576, 256, 0, stream>>>(whh, wpack);

  const uint4* wpc = (const uint4*)wpack;
  const _Float16* igc = igb;
  void* kargs[] = {(void*)&wpc, (void*)&igc, (void*)&bias_n, (void*)&pairb,
                   (void*)&x, (void*)&wih, (void*)&bias, (void*)&prog};
  hipLaunchCooperativeKernel(k_fused, dim3(256), dim3(512), kargs, 0, stream);

  k_out<<<250, 256, 0, stream>>>(wout, bout, bextra, pairb, out);
}

// Round 14
// 43980.704 us; speedup vs baseline: 1.4488x; 1.3161x over previous
//
#include <hip/hip_runtime.h>
#include <hip/hip_bf16.h>

typedef unsigned int u32;
typedef unsigned short u16;
typedef unsigned long long u64;
using half2_t = __attribute__((ext_vector_type(2))) _Float16;
using half8   = __attribute__((ext_vector_type(8))) _Float16;
using f32x4   = __attribute__((ext_vector_type(4))) float;
using u32x4   = __attribute__((ext_vector_type(4))) u32;

// Problem dims
#define TT 16384
#define HDIM 2048
#define N3H 6144
#define ODIM 1000

// Workspace layout (bytes). Total = 318,785,536 (~304 MB)
#define WS_WPACK 0ull                 // 25,165,824  : W_hh packed f16 pairs
#define WS_PROG  25165824ull          // 512         : progress counters [128] u32
#define WS_IG    117440512ull         // 201,326,592 : igates f16 [T][6144]
#define WS_PAIR  318767104ull         // 16,384      : h publish {tag16|f16} [2][2048] u32
#define WS_NEED  318785536ull

#if __has_builtin(__builtin_amdgcn_fdot2)
__device__ __forceinline__ float fdot2u(u32 a, u32 b, float c) {
  return __builtin_amdgcn_fdot2(__builtin_bit_cast(half2_t, a),
                                __builtin_bit_cast(half2_t, b), c, false);
}
#else
__device__ __forceinline__ float fdot2u(u32 a, u32 b, float c) {
  half2_t x = __builtin_bit_cast(half2_t, a), y = __builtin_bit_cast(half2_t, b);
  return c + (float)x[0] * (float)y[0] + (float)x[1] * (float)y[1];
}
#endif

// Coherent coalesced 16B load: sc0+sc1 -> served at the device coherence
// point; each dword individually atomic (all the in-band tag scheme needs).
__device__ __forceinline__ u32x4 poll_load16(const u32* p) {
  u32x4 r;
  asm volatile("global_load_dwordx4 %0, %1, off sc0 sc1\n\ts_waitcnt vmcnt(0)"
               : "=&v"(r) : "v"(p));
  return r;
}
// Coherent dword load at the CP.
__device__ __forceinline__ u32 cload4_cp(const u32* p) {
  u32 r;
  asm volatile("global_load_dword %0, %1, off sc0 sc1\n\ts_waitcnt vmcnt(0)"
               : "=&v"(r) : "v"(p));
  return r;
}
// Three coherent ushort loads, one RTT (single vmcnt drain). NOTE: the drain
// doubles as the pre-poll delay that lets publishes land before the first
// poll round (R10 vs R9/R11/R13 evidence — do not remove).
__device__ __forceinline__ void ld3_f16_cp(const _Float16* p0, const _Float16* p1,
                                           const _Float16* p2, float& a, float& b, float& c) {
  u32 ra, rb, rc;
  asm volatile("global_load_ushort %0, %3, off sc0 sc1\n\t"
               "global_load_ushort %1, %4, off sc0 sc1\n\t"
               "global_load_ushort %2, %5, off sc0 sc1\n\t"
               "s_waitcnt vmcnt(0)"
               : "=&v"(ra), "=&v"(rb), "=&v"(rc)
               : "v"(p0), "v"(p1), "v"(p2));
  a = (float)__builtin_bit_cast(_Float16, (u16)ra);
  b = (float)__builtin_bit_cast(_Float16, (u16)rb);
  c = (float)__builtin_bit_cast(_Float16, (u16)rc);
}
// Coherent 2-byte store at the CP (write-through).
__device__ __forceinline__ void st2_cp(_Float16* p, _Float16 v) {
  u32 u = (u32)__builtin_bit_cast(u16, v);
  asm volatile("global_store_short %0, %1, off sc0 sc1" :: "v"(p), "v"(u) : "memory");
}

// ---------------- zero helpers (every launch: clears stale tags/counters) ----
__global__ void k_zero(u32* p) {
  p[blockIdx.x * 256 + threadIdx.x] = 0u;  // pair: 4096 dwords
}
__global__ void k_zero_n(u32* p, int n) {
  int i = blockIdx.x * 256 + threadIdx.x;
  if (i < n) p[i] = 0u;
}

// ---------------- pack W_hh into per-(hrow,wave,lane) f16-pair layout --------
// (verbatim R3/R9) dword idx = hrow*3072 + c*256 + lane*4 + q ; dl=c*4+q
// g=dl/16 ; m=dl%16 ; value = (W_hh[g*2048+hrow][2*(lane*16+m)], ...+1)
__global__ __launch_bounds__(256) void k_pack(const float* __restrict__ whh,
                                              u32* __restrict__ outp) {
  u32 idx = blockIdx.x * 256 + threadIdx.x;  // < 6,291,456
  u32 hrow = idx / 3072;
  u32 rem = idx - hrow * 3072;
  u32 c = rem >> 8;
  u32 lane = (rem >> 2) & 63;
  u32 q = rem & 3;
  u32 dl = c * 4 + q;
  u32 g = dl >> 4;
  u32 m = dl & 15;
  u32 kp = lane * 16 + m;
  const float* src = whh + (size_t)(g * 2048 + hrow) * 2048 + 2 * kp;
  half2_t p;
  p[0] = (_Float16)src[0];
  p[1] = (_Float16)src[1];
  outp[idx] = __builtin_bit_cast(u32, p);
}

__device__ __forceinline__ u32 packf16(float a, float b) {
  half2_t p;
  p[0] = (_Float16)a;
  p[1] = (_Float16)b;
  return __builtin_bit_cast(u32, p);
}

// ---------------- fused coop kernel: 256 WGs x 512 thr -----------------------
// WG 0..127  : GRU scan (R9 core), rows r0 = wg*16 + 2v per wave v.
// WG 128..255: igates GEMM helpers. C[m][n] = sum_k x[m][k]*Wih[n][k] + bias[n],
//   fp32 inputs converted to f16 during LDS staging, 128x128 tiles, 8 waves
//   (2x4), mfma 16x16x32. Stores via sc0sc1 (write-through to CP); after each
//   tile: vmcnt(0) drain -> barrier -> atomicAdd(prog[mblock]). Scan gates its
//   igate reads on prog[mblock]==48 and reads them sc0sc1 (always CP-fresh).
__global__ __launch_bounds__(512) void k_fused(const uint4* __restrict__ wpack,
                                               const _Float16* __restrict__ ig,
                                               const float* __restrict__ bias_n,
                                               u32* pair,
                                               const float* __restrict__ X,
                                               const float* __restrict__ Wih,
                                               const float* __restrict__ bias,
                                               u32* prog) {
  __shared__ __align__(16) u32 smem[4096];  // 16KB: scan uses 1280, gemm 4096
  const int tid = threadIdx.x;

  if (blockIdx.x < 128) {
    // ======================= SCAN (verbatim R9 core) ========================
    u32* lds_h = smem;  // 1024 f16-pair dwords + pad 4/16
    const int l = tid & 63, v = tid >> 6;
    const int wg = blockIdx.x;
    const int r0 = wg * 16 + v * 2;
    const int my_row = r0 + (l & 1);

    u32 wdwA[48], wdwB[48];
    {
      const uint4* wpA = wpack + (size_t)r0 * 768 + l;
      const uint4* wpB = wpA + 768;  // row r0+1
#pragma unroll
      for (int c = 0; c < 12; ++c) {
        uint4 a = wpA[(size_t)c * 64];
        wdwA[c * 4] = a.x; wdwA[c * 4 + 1] = a.y; wdwA[c * 4 + 2] = a.z; wdwA[c * 4 + 3] = a.w;
      }
#pragma unroll
      for (int c = 0; c < 12; ++c) {
        uint4 b = wpB[(size_t)c * 64];
        wdwB[c * 4] = b.x; wdwB[c * 4 + 1] = b.y; wdwB[c * 4 + 2] = b.z; wdwB[c * 4 + 3] = b.w;
      }
    }
    const float bn = bias_n[my_row];
    float hm = 0.f;  // fp32 master state for my_row (valid in lanes 0,1)
    u32 hreg[16];
#pragma unroll
    for (int m = 0; m < 16; ++m) hreg[m] = 0;  // h(0) = 0

    int ready_blk = 0;
    {  // gate igates m-block 0, then load row 0
      for (;;) {
        u32 c = cload4_cp(prog);
        if (c >= 48u) break;
        __builtin_amdgcn_s_sleep(8);
      }
      ready_blk = 1;
    }
    float ig0, ig1, ig2;
    ld3_f16_cp(ig + my_row, ig + 2048 + my_row, ig + 4096 + my_row, ig0, ig1, ig2);

    for (int t = 0; t < TT; ++t) {
      float igr = ig0, igz = ig1, ign = ig2;
      float a0 = 0.f, a1 = 0.f, a2 = 0.f, a3 = 0.f, a4 = 0.f, a5 = 0.f;
      float b0 = 0.f, b1 = 0.f, b2 = 0.f, b3 = 0.f, b4 = 0.f, b5 = 0.f;
#pragma unroll
      for (int m = 0; m < 16; m += 2) {
        a0 = fdot2u(wdwA[m],          hreg[m],     a0);
        b0 = fdot2u(wdwA[m + 1],      hreg[m + 1], b0);
        a1 = fdot2u(wdwA[16 + m],     hreg[m],     a1);
        b1 = fdot2u(wdwA[16 + m + 1], hreg[m + 1], b1);
        a2 = fdot2u(wdwA[32 + m],     hreg[m],     a2);
        b2 = fdot2u(wdwA[32 + m + 1], hreg[m + 1], b2);
        a3 = fdot2u(wdwB[m],          hreg[m],     a3);
        b3 = fdot2u(wdwB[m + 1],      hreg[m + 1], b3);
        a4 = fdot2u(wdwB[16 + m],     hreg[m],     a4);
        b4 = fdot2u(wdwB[16 + m + 1], hreg[m + 1], b4);
        a5 = fdot2u(wdwB[32 + m],     hreg[m],     a5);
        b5 = fdot2u(wdwB[32 + m + 1], hreg[m + 1], b5);
      }
      float s0 = a0 + b0, s1 = a1 + b1, s2 = a2 + b2;
      float s3 = a3 + b3, s4 = a4 + b4, s5 = a5 + b5;
#pragma unroll
      for (int off = 1; off < 64; off <<= 1) {
        s0 += __shfl_xor(s0, off, 64);
        s1 += __shfl_xor(s1, off, 64);
        s2 += __shfl_xor(s2, off, 64);
        s3 += __shfl_xor(s3, off, 64);
        s4 += __shfl_xor(s4, off, 64);
        s5 += __shfl_xor(s5, off, 64);
      }
      u32* pdst = pair + (((t + 1) & 1) << 11);
      u32 pk = 0;
      if (l < 2) {
        float sr = l ? s3 : s0, sz = l ? s4 : s1, sn = l ? s5 : s2;
        float r = 1.f / (1.f + __expf(-(igr + sr)));
        float z = 1.f / (1.f + __expf(-(igz + sz)));
        float nx = ign + r * (sn + bn);
        float e = __expf(-2.f * nx);
        float n = (1.f - e) / (1.f + e);
        hm = n + z * (hm - n);
        pk = ((u32)(t + 1) << 16) | (u32)__builtin_bit_cast(u16, (_Float16)hm);
      }
      u32 pk1 = __shfl(pk, 1, 64);  // row r0+1's packed dword -> lane 0
      if (l == 0)
        __hip_atomic_store((u64*)(pdst + r0), (u64)pk | ((u64)pk1 << 32),
                           __ATOMIC_RELAXED, __HIP_MEMORY_SCOPE_AGENT);
      if (t == TT - 1) break;
      {  // gate + prefetch next igates row (CP loads; drain = pre-poll delay)
        int nb = (t + 1) >> 7;
        if (nb >= ready_blk) {
          const u32* pb = prog + nb;
          for (;;) {
            u32 c = cload4_cp(pb);
            if (c >= 48u) break;
            __builtin_amdgcn_s_sleep(8);
          }
          ready_blk = nb + 1;
        }
        const _Float16* igp = ig + (size_t)(t + 1) * N3H;
        ld3_f16_cp(igp + my_row, igp + 2048 + my_row, igp + 4096 + my_row, ig0, ig1, ig2);
      }
      // poll own 4 rows (verbatim R3/R9)
      const u32 tgt = (u32)(t + 1) << 16;
      const u32* pp = pdst + 4 * tid;
      __builtin_amdgcn_s_sleep(2);
      u32x4 d;
      for (;;) {
        d = poll_load16(pp);
        u32 bad = ((d[0] ^ tgt) | (d[1] ^ tgt) | (d[2] ^ tgt) | (d[3] ^ tgt)) & 0xFFFF0000u;
        if (!bad) break;
        __builtin_amdgcn_s_sleep(2);
      }
      __syncthreads();  // all local waves done reading lds_h of prev step
      u32 p0 = (d[0] & 0xFFFFu) | (d[1] << 16);
      u32 p1 = (d[2] & 0xFFFFu) | (d[3] << 16);
      u32* dst = lds_h + 2 * tid + ((tid >> 3) << 2);  // pad 4 dwords per 16
      dst[0] = p0;
      dst[1] = p1;
      __syncthreads();
#pragma unroll
      for (int i = 0; i < 4; ++i) {
        uint4 vv = *(const uint4*)(lds_h + l * 20 + i * 4);
        hreg[i * 4] = vv.x; hreg[i * 4 + 1] = vv.y; hreg[i * 4 + 2] = vv.z; hreg[i * 4 + 3] = vv.w;
      }
    }
  } else {
    // ======================= GEMM HELPERS ===================================
    _Float16* As = (_Float16*)smem;           // [128][32] f16 = 8KB
    _Float16* Bs = (_Float16*)(smem + 2048);  // [128][32] f16 = 8KB
    const int hid = blockIdx.x - 128;
    const int l = tid & 63, w = tid >> 6;
    const int wr = w >> 2, wc = w & 3;        // 2x4 wave grid
    const int srow = tid >> 2;                // 0..127
    const int scol = (tid & 3) << 3;          // 0,8,16,24

    for (int tile = hid; tile < 6144; tile += 128) {
      const int mb = tile / 48, nb = tile - mb * 48;
      const int m0 = mb * 128, n0 = nb * 128;
      f32x4 acc[4][2] = {};

      for (int k0 = 0; k0 < HDIM; k0 += 32) {
        __syncthreads();
        const float* ap = X + (size_t)(m0 + srow) * HDIM + k0 + scol;
        const float* bp = Wih + (size_t)(n0 + srow) * HDIM + k0 + scol;
        float4 aL = *(const float4*)ap, aH = *(const float4*)(ap + 4);
        float4 bL = *(const float4*)bp, bH = *(const float4*)(bp + 4);
        uint4 av4 = make_uint4(packf16(aL.x, aL.y), packf16(aL.z, aL.w),
                               packf16(aH.x, aH.y), packf16(aH.z, aH.w));
        uint4 bv4 = make_uint4(packf16(bL.x, bL.y), packf16(bL.z, bL.w),
                               packf16(bH.x, bH.y), packf16(bH.z, bH.w));
        *(uint4*)(As + srow * 32 + scol) = av4;
        *(uint4*)(Bs + srow * 32 + scol) = bv4;
        __syncthreads();
        half8 av[4], bv[2];
#pragma unroll
        for (int mi = 0; mi < 4; ++mi)
          av[mi] = *(const half8*)(As + (wr * 64 + mi * 16 + (l & 15)) * 32 + (l >> 4) * 8);
#pragma unroll
        for (int ni = 0; ni < 2; ++ni)
          bv[ni] = *(const half8*)(Bs + (wc * 32 + ni * 16 + (l & 15)) * 32 + (l >> 4) * 8);
#pragma unroll
        for (int mi = 0; mi < 4; ++mi)
#pragma unroll
          for (int ni = 0; ni < 2; ++ni)
            acc[mi][ni] = __builtin_amdgcn_mfma_f32_16x16x32_f16(av[mi], bv[ni], acc[mi][ni], 0, 0, 0);
      }
      _Float16* Cout = (_Float16*)ig;
#pragma unroll
      for (int ni = 0; ni < 2; ++ni) {
        int col = n0 + wc * 32 + ni * 16 + (l & 15);
        float bb = bias[col];
#pragma unroll
        for (int mi = 0; mi < 4; ++mi) {
          int rbase = m0 + wr * 64 + mi * 16 + (l >> 4) * 4;
#pragma unroll
          for (int r = 0; r < 4; ++r)
            st2_cp(Cout + (size_t)(rbase + r) * N3H + col,
                   (_Float16)(acc[mi][ni][r] + bb));
        }
      }
      asm volatile("s_waitcnt vmcnt(0)" ::: "memory");  // data at CP
      __syncthreads();                                   // all threads drained
      if (tid == 0)
        __hip_atomic_fetch_add(prog + mb, 1u, __ATOMIC_RELAXED,
                               __HIP_MEMORY_SCOPE_AGENT);
    }
  }
}

// ---------------- final projection: out = w_out @ h_final + b_out + b_extra --
// h_final is in pair buffer 0 (TT even), f16 in low 16 bits of each dword.
__global__ __launch_bounds__(256) void k_out(const float* __restrict__ wout,
                                             const float* __restrict__ bout,
                                             const float* __restrict__ bextra,
                                             const u32* __restrict__ hp,
                                             float* __restrict__ out) {
  const int l = threadIdx.x & 63;
  const int o = blockIdx.x * 4 + (threadIdx.x >> 6);
  if (o >= ODIM) return;
  const float* wr = wout + (size_t)o * HDIM;
  float acc = 0.f;
#pragma unroll
  for (int i = 0; i < 8; ++i) {
    int k4 = i * 256 + l * 4;
    uint4 hd = *(const uint4*)(hp + k4);
    float4 wv = *(const float4*)(wr + k4);
    acc += wv.x * (float)__builtin_bit_cast(_Float16, (u16)(hd.x & 0xFFFFu));
    acc += wv.y * (float)__builtin_bit_cast(_Float16, (u16)(hd.y & 0xFFFFu));
    acc += wv.z * (float)__builtin_bit_cast(_Float16, (u16)(hd.z & 0xFFFFu));
    acc += wv.w * (float)__builtin_bit_cast(_Float16, (u16)(hd.w & 0xFFFFu));
  }
#pragma unroll
  for (int off = 1; off < 64; off <<= 1) acc += __shfl_xor(acc, off, 64);
  if (l == 0) out[o] = acc + bout[o] + bextra[o];
}

// sentinel if workspace too small: absmax ~= 1e6 + ws_size_in_MB (debug channel)
__global__ void k_dbg(float* out, float v) {
  int i = blockIdx.x * 256 + threadIdx.x;
  if (i < ODIM) out[i] = v;
}

extern "C" void kernel_launch(void* const* d_in, const int* in_sizes, int n_in,
                              void* d_out, int out_size, void* d_ws, size_t ws_size,
                              hipStream_t stream) {
  const float* x      = (const float*)d_in[0];
  const float* wih    = (const float*)d_in[1];
  const float* whh    = (const float*)d_in[2];
  const float* bias   = (const float*)d_in[3];
  const float* bias_n = (const float*)d_in[4];
  const float* wout   = (const float*)d_in[5];
  const float* bout   = (const float*)d_in[6];
  const float* bextra = (const float*)d_in[7];
  float* out = (float*)d_out;

  if (ws_size < WS_NEED) {
    k_dbg<<<4, 256, 0, stream>>>(out, 1.0e6f + (float)(ws_size / 1048576ull));
    return;
  }

  char* ws = (char*)d_ws;
  u32*      wpack = (u32*)(ws + WS_WPACK);
  u32*      prog  = (u32*)(ws + WS_PROG);
  _Float16* igb   = (_Float16*)(ws + WS_IG);
  u32*      pairb = (u32*)(ws + WS_PAIR);

  k_zero<<<16, 256, 0, stream>>>(pairb);
  k_zero_n<<<1, 256, 0, stream>>>(prog, 128);
  k_pack<<<24576, 256, 0, stream>>>(whh, wpack);

  const uint4* wpc = (const uint4*)wpack;
  const _Float16* igc = igb;
  void* kargs[] = {(void*)&wpc, (void*)&igc, (void*)&bias_n, (void*)&pairb,
                   (void*)&x, (void*)&wih, (void*)&bias, (void*)&prog};
  hipLaunchCooperativeKernel(k_fused, dim3(256), dim3(512), kargs, 0, stream);

  k_out<<<250, 256, 0, stream>>>(wout, bout, bextra, pairb, out);
}

// Round 15
// 34522.385 us; speedup vs baseline: 1.8457x; 1.2740x over previous
//
#include <hip/hip_runtime.h>
#include <hip/hip_bf16.h>

typedef unsigned int u32;
typedef unsigned short u16;
typedef unsigned long long u64;
using half2_t = __attribute__((ext_vector_type(2))) _Float16;
using half8   = __attribute__((ext_vector_type(8))) _Float16;
using f32x4   = __attribute__((ext_vector_type(4))) float;
using u32x4   = __attribute__((ext_vector_type(4))) u32;

// Problem dims
#define TT 16384
#define HDIM 2048
#define N3H 6144
#define ODIM 1000

// Workspace layout (bytes). Total = 318,785,536 (~304 MB)
#define WS_WPACK 0ull                 // 25,165,824  : W_hh packed f16 pairs
#define WS_PROG  25165824ull          // 512         : progress counters [128] u32
#define WS_IG    117440512ull         // 201,326,592 : igates f16 [T][6144]
#define WS_PAIR  318767104ull         // 16,384      : h publish {tag16|f16} [2][2048] u32
#define WS_NEED  318785536ull

#if __has_builtin(__builtin_amdgcn_fdot2)
__device__ __forceinline__ float fdot2u(u32 a, u32 b, float c) {
  return __builtin_amdgcn_fdot2(__builtin_bit_cast(half2_t, a),
                                __builtin_bit_cast(half2_t, b), c, false);
}
#else
__device__ __forceinline__ float fdot2u(u32 a, u32 b, float c) {
  half2_t x = __builtin_bit_cast(half2_t, a), y = __builtin_bit_cast(half2_t, b);
  return c + (float)x[0] * (float)y[0] + (float)x[1] * (float)y[1];
}
#endif

// Coherent coalesced 16B load: sc0+sc1 -> served at the device coherence
// point; each dword individually atomic (all the in-band tag scheme needs).
__device__ __forceinline__ u32x4 poll_load16(const u32* p) {
  u32x4 r;
  asm volatile("global_load_dwordx4 %0, %1, off sc0 sc1\n\ts_waitcnt vmcnt(0)"
               : "=&v"(r) : "v"(p));
  return r;
}
// Coherent dword load at the CP.
__device__ __forceinline__ u32 cload4_cp(const u32* p) {
  u32 r;
  asm volatile("global_load_dword %0, %1, off sc0 sc1\n\ts_waitcnt vmcnt(0)"
               : "=&v"(r) : "v"(p));
  return r;
}
// Three coherent ushort loads, one RTT (single vmcnt drain). NOTE: the drain
// doubles as part of the pre-poll delay that lets publishes land before the
// first poll round (R10 vs R9/R11/R13 evidence — do not remove).
__device__ __forceinline__ void ld3_f16_cp(const _Float16* p0, const _Float16* p1,
                                           const _Float16* p2, float& a, float& b, float& c) {
  u32 ra, rb, rc;
  asm volatile("global_load_ushort %0, %3, off sc0 sc1\n\t"
               "global_load_ushort %1, %4, off sc0 sc1\n\t"
               "global_load_ushort %2, %5, off sc0 sc1\n\t"
               "s_waitcnt vmcnt(0)"
               : "=&v"(ra), "=&v"(rb), "=&v"(rc)
               : "v"(p0), "v"(p1), "v"(p2));
  a = (float)__builtin_bit_cast(_Float16, (u16)ra);
  b = (float)__builtin_bit_cast(_Float16, (u16)rb);
  c = (float)__builtin_bit_cast(_Float16, (u16)rc);
}
// Coherent 2-byte store at the CP (write-through).
__device__ __forceinline__ void st2_cp(_Float16* p, _Float16 v) {
  u32 u = (u32)__builtin_bit_cast(u16, v);
  asm volatile("global_store_short %0, %1, off sc0 sc1" :: "v"(p), "v"(u) : "memory");
}

// ---------------- zero helpers (every launch: clears stale tags/counters) ----
__global__ void k_zero(u32* p) {
  p[blockIdx.x * 256 + threadIdx.x] = 0u;  // pair: 4096 dwords
}
__global__ void k_zero_n(u32* p, int n) {
  int i = blockIdx.x * 256 + threadIdx.x;
  if (i < n) p[i] = 0u;
}

// ---------------- pack W_hh into per-(hrow,wave,lane) f16-pair layout --------
// (verbatim R3/R9) dword idx = hrow*3072 + c*256 + lane*4 + q ; dl=c*4+q
// g=dl/16 ; m=dl%16 ; value = (W_hh[g*2048+hrow][2*(lane*16+m)], ...+1)
__global__ __launch_bounds__(256) void k_pack(const float* __restrict__ whh,
                                              u32* __restrict__ outp) {
  u32 idx = blockIdx.x * 256 + threadIdx.x;  // < 6,291,456
  u32 hrow = idx / 3072;
  u32 rem = idx - hrow * 3072;
  u32 c = rem >> 8;
  u32 lane = (rem >> 2) & 63;
  u32 q = rem & 3;
  u32 dl = c * 4 + q;
  u32 g = dl >> 4;
  u32 m = dl & 15;
  u32 kp = lane * 16 + m;
  const float* src = whh + (size_t)(g * 2048 + hrow) * 2048 + 2 * kp;
  half2_t p;
  p[0] = (_Float16)src[0];
  p[1] = (_Float16)src[1];
  outp[idx] = __builtin_bit_cast(u32, p);
}

__device__ __forceinline__ u32 packf16(float a, float b) {
  half2_t p;
  p[0] = (_Float16)a;
  p[1] = (_Float16)b;
  return __builtin_bit_cast(u32, p);
}

// ---------------- fused coop kernel: 256 WGs x 512 thr -----------------------
// WG 0..127  : GRU scan (R9 core), rows r0 = wg*16 + 2v per wave v.
// WG 128..255: igates GEMM helpers. Stores via sc0sc1; after each tile:
//   vmcnt(0) drain -> barrier -> atomicAdd(prog[mblock]). Scan gates igate
//   reads on prog[mblock]==48 and reads them sc0sc1 (always CP-fresh).
// R15 change vs R14 (single, isolated): initial pre-poll backoff s_sleep(2)
// -> s_sleep(10) (~0.27us) so publishes land before the first poll round.
__global__ __launch_bounds__(512) void k_fused(const uint4* __restrict__ wpack,
                                               const _Float16* __restrict__ ig,
                                               const float* __restrict__ bias_n,
                                               u32* pair,
                                               const float* __restrict__ X,
                                               const float* __restrict__ Wih,
                                               const float* __restrict__ bias,
                                               u32* prog) {
  __shared__ __align__(16) u32 smem[4096];  // 16KB: scan uses 1280, gemm 4096
  const int tid = threadIdx.x;

  if (blockIdx.x < 128) {
    // ======================= SCAN (R9/R10 core) =============================
    u32* lds_h = smem;  // 1024 f16-pair dwords + pad 4/16
    const int l = tid & 63, v = tid >> 6;
    const int wg = blockIdx.x;
    const int r0 = wg * 16 + v * 2;
    const int my_row = r0 + (l & 1);

    u32 wdwA[48], wdwB[48];
    {
      const uint4* wpA = wpack + (size_t)r0 * 768 + l;
      const uint4* wpB = wpA + 768;  // row r0+1
#pragma unroll
      for (int c = 0; c < 12; ++c) {
        uint4 a = wpA[(size_t)c * 64];
        wdwA[c * 4] = a.x; wdwA[c * 4 + 1] = a.y; wdwA[c * 4 + 2] = a.z; wdwA[c * 4 + 3] = a.w;
      }
#pragma unroll
      for (int c = 0; c < 12; ++c) {
        uint4 b = wpB[(size_t)c * 64];
        wdwB[c * 4] = b.x; wdwB[c * 4 + 1] = b.y; wdwB[c * 4 + 2] = b.z; wdwB[c * 4 + 3] = b.w;
      }
    }
    const float bn = bias_n[my_row];
    float hm = 0.f;  // fp32 master state for my_row (valid in lanes 0,1)
    u32 hreg[16];
#pragma unroll
    for (int m = 0; m < 16; ++m) hreg[m] = 0;  // h(0) = 0

    int ready_blk = 0;
    {  // gate igates m-block 0, then load row 0
      for (;;) {
        u32 c = cload4_cp(prog);
        if (c >= 48u) break;
        __builtin_amdgcn_s_sleep(8);
      }
      ready_blk = 1;
    }
    float ig0, ig1, ig2;
    ld3_f16_cp(ig + my_row, ig + 2048 + my_row, ig + 4096 + my_row, ig0, ig1, ig2);

    for (int t = 0; t < TT; ++t) {
      float igr = ig0, igz = ig1, ign = ig2;
      float a0 = 0.f, a1 = 0.f, a2 = 0.f, a3 = 0.f, a4 = 0.f, a5 = 0.f;
      float b0 = 0.f, b1 = 0.f, b2 = 0.f, b3 = 0.f, b4 = 0.f, b5 = 0.f;
#pragma unroll
      for (int m = 0; m < 16; m += 2) {
        a0 = fdot2u(wdwA[m],          hreg[m],     a0);
        b0 = fdot2u(wdwA[m + 1],      hreg[m + 1], b0);
        a1 = fdot2u(wdwA[16 + m],     hreg[m],     a1);
        b1 = fdot2u(wdwA[16 + m + 1], hreg[m + 1], b1);
        a2 = fdot2u(wdwA[32 + m],     hreg[m],     a2);
        b2 = fdot2u(wdwA[32 + m + 1], hreg[m + 1], b2);
        a3 = fdot2u(wdwB[m],          hreg[m],     a3);
        b3 = fdot2u(wdwB[m + 1],      hreg[m + 1], b3);
        a4 = fdot2u(wdwB[16 + m],     hreg[m],     a4);
        b4 = fdot2u(wdwB[16 + m + 1], hreg[m + 1], b4);
        a5 = fdot2u(wdwB[32 + m],     hreg[m],     a5);
        b5 = fdot2u(wdwB[32 + m + 1], hreg[m + 1], b5);
      }
      float s0 = a0 + b0, s1 = a1 + b1, s2 = a2 + b2;
      float s3 = a3 + b3, s4 = a4 + b4, s5 = a5 + b5;
#pragma unroll
      for (int off = 1; off < 64; off <<= 1) {
        s0 += __shfl_xor(s0, off, 64);
        s1 += __shfl_xor(s1, off, 64);
        s2 += __shfl_xor(s2, off, 64);
        s3 += __shfl_xor(s3, off, 64);
        s4 += __shfl_xor(s4, off, 64);
        s5 += __shfl_xor(s5, off, 64);
      }
      u32* pdst = pair + (((t + 1) & 1) << 11);
      u32 pk = 0;
      if (l < 2) {
        float sr = l ? s3 : s0, sz = l ? s4 : s1, sn = l ? s5 : s2;
        float r = 1.f / (1.f + __expf(-(igr + sr)));
        float z = 1.f / (1.f + __expf(-(igz + sz)));
        float nx = ign + r * (sn + bn);
        float e = __expf(-2.f * nx);
        float n = (1.f - e) / (1.f + e);
        hm = n + z * (hm - n);
        pk = ((u32)(t + 1) << 16) | (u32)__builtin_bit_cast(u16, (_Float16)hm);
      }
      u32 pk1 = __shfl(pk, 1, 64);  // row r0+1's packed dword -> lane 0
      if (l == 0)
        __hip_atomic_store((u64*)(pdst + r0), (u64)pk | ((u64)pk1 << 32),
                           __ATOMIC_RELAXED, __HIP_MEMORY_SCOPE_AGENT);
      if (t == TT - 1) break;
      {  // gate + prefetch next igates row (CP loads; drain = pre-poll delay)
        int nb = (t + 1) >> 7;
        if (nb >= ready_blk) {
          const u32* pb = prog + nb;
          for (;;) {
            u32 c = cload4_cp(pb);
            if (c >= 48u) break;
            __builtin_amdgcn_s_sleep(8);
          }
          ready_blk = nb + 1;
        }
        const _Float16* igp = ig + (size_t)(t + 1) * N3H;
        ld3_f16_cp(igp + my_row, igp + 2048 + my_row, igp + 4096 + my_row, ig0, ig1, ig2);
      }
      // poll own 4 rows; longer initial backoff so first round succeeds.
      const u32 tgt = (u32)(t + 1) << 16;
      const u32* pp = pdst + 4 * tid;
      __builtin_amdgcn_s_sleep(10);  // R15: was s_sleep(2)
      u32x4 d;
      for (;;) {
        d = poll_load16(pp);
        u32 bad = ((d[0] ^ tgt) | (d[1] ^ tgt) | (d[2] ^ tgt) | (d[3] ^ tgt)) & 0xFFFF0000u;
        if (!bad) break;
        __builtin_amdgcn_s_sleep(2);
      }
      __syncthreads();  // all local waves done reading lds_h of prev step
      u32 p0 = (d[0] & 0xFFFFu) | (d[1] << 16);
      u32 p1 = (d[2] & 0xFFFFu) | (d[3] << 16);
      u32* dst = lds_h + 2 * tid + ((tid >> 3) << 2);  // pad 4 dwords per 16
      dst[0] = p0;
      dst[1] = p1;
      __syncthreads();
#pragma unroll
      for (int i = 0; i < 4; ++i) {
        uint4 vv = *(const uint4*)(lds_h + l * 20 + i * 4);
        hreg[i * 4] = vv.x; hreg[i * 4 + 1] = vv.y; hreg[i * 4 + 2] = vv.z; hreg[i * 4 + 3] = vv.w;
      }
    }
  } else {
    // ======================= GEMM HELPERS ===================================
    _Float16* As = (_Float16*)smem;           // [128][32] f16 = 8KB
    _Float16* Bs = (_Float16*)(smem + 2048);  // [128][32] f16 = 8KB
    const int hid = blockIdx.x - 128;
    const int l = tid & 63, w = tid >> 6;
    const int wr = w >> 2, wc = w & 3;        // 2x4 wave grid
    const int srow = tid >> 2;                // 0..127
    const int scol = (tid & 3) << 3;          // 0,8,16,24

    for (int tile = hid; tile < 6144; tile += 128) {
      const int mb = tile / 48, nb = tile - mb * 48;
      const int m0 = mb * 128, n0 = nb * 128;
      f32x4 acc[4][2] = {};

      for (int k0 = 0; k0 < HDIM; k0 += 32) {
        __syncthreads();
        const float* ap = X + (size_t)(m0 + srow) * HDIM + k0 + scol;
        const float* bp = Wih + (size_t)(n0 + srow) * HDIM + k0 + scol;
        float4 aL = *(const float4*)ap, aH = *(const float4*)(ap + 4);
        float4 bL = *(const float4*)bp, bH = *(const float4*)(bp + 4);
        uint4 av4 = make_uint4(packf16(aL.x, aL.y), packf16(aL.z, aL.w),
                               packf16(aH.x, aH.y), packf16(aH.z, aH.w));
        uint4 bv4 = make_uint4(packf16(bL.x, bL.y), packf16(bL.z, bL.w),
                               packf16(bH.x, bH.y), packf16(bH.z, bH.w));
        *(uint4*)(As + srow * 32 + scol) = av4;
        *(uint4*)(Bs + srow * 32 + scol) = bv4;
        __syncthreads();
        half8 av[4], bv[2];
#pragma unroll
        for (int mi = 0; mi < 4; ++mi)
          av[mi] = *(const half8*)(As + (wr * 64 + mi * 16 + (l & 15)) * 32 + (l >> 4) * 8);
#pragma unroll
        for (int ni = 0; ni < 2; ++ni)
          bv[ni] = *(const half8*)(Bs + (wc * 32 + ni * 16 + (l & 15)) * 32 + (l >> 4) * 8);
#pragma unroll
        for (int mi = 0; mi < 4; ++mi)
#pragma unroll
          for (int ni = 0; ni < 2; ++ni)
            acc[mi][ni] = __builtin_amdgcn_mfma_f32_16x16x32_f16(av[mi], bv[ni], acc[mi][ni], 0, 0, 0);
      }
      _Float16* Cout = (_Float16*)ig;
#pragma unroll
      for (int ni = 0; ni < 2; ++ni) {
        int col = n0 + wc * 32 + ni * 16 + (l & 15);
        float bb = bias[col];
#pragma unroll
        for (int mi = 0; mi < 4; ++mi) {
          int rbase = m0 + wr * 64 + mi * 16 + (l >> 4) * 4;
#pragma unroll
          for (int r = 0; r < 4; ++r)
            st2_cp(Cout + (size_t)(rbase + r) * N3H + col,
                   (_Float16)(acc[mi][ni][r] + bb));
        }
      }
      asm volatile("s_waitcnt vmcnt(0)" ::: "memory");  // data at CP
      __syncthreads();                                   // all threads drained
      if (tid == 0)
        __hip_atomic_fetch_add(prog + mb, 1u, __ATOMIC_RELAXED,
                               __HIP_MEMORY_SCOPE_AGENT);
    }
  }
}

// ---------------- final projection: out = w_out @ h_final + b_out + b_extra --
// h_final is in pair buffer 0 (TT even), f16 in low 16 bits of each dword.
__global__ __launch_bounds__(256) void k_out(const float* __restrict__ wout,
                                             const float* __restrict__ bout,
                                             const float* __restrict__ bextra,
                                             const u32* __restrict__ hp,
                                             float* __restrict__ out) {
  const int l = threadIdx.x & 63;
  const int o = blockIdx.x * 4 + (threadIdx.x >> 6);
  if (o >= ODIM) return;
  const float* wr = wout + (size_t)o * HDIM;
  float acc = 0.f;
#pragma unroll
  for (int i = 0; i < 8; ++i) {
    int k4 = i * 256 + l * 4;
    uint4 hd = *(const uint4*)(hp + k4);
    float4 wv = *(const float4*)(wr + k4);
    acc += wv.x * (float)__builtin_bit_cast(_Float16, (u16)(hd.x & 0xFFFFu));
    acc += wv.y * (float)__builtin_bit_cast(_Float16, (u16)(hd.y & 0xFFFFu));
    acc += wv.z * (float)__builtin_bit_cast(_Float16, (u16)(hd.z & 0xFFFFu));
    acc += wv.w * (float)__builtin_bit_cast(_Float16, (u16)(hd.w & 0xFFFFu));
  }
#pragma unroll
  for (int off = 1; off < 64; off <<= 1) acc += __shfl_xor(acc, off, 64);
  if (l == 0) out[o] = acc + bout[o] + bextra[o];
}

// sentinel if workspace too small: absmax ~= 1e6 + ws_size_in_MB (debug channel)
__global__ void k_dbg(float* out, float v) {
  int i = blockIdx.x * 256 + threadIdx.x;
  if (i < ODIM) out[i] = v;
}

extern "C" void kernel_launch(void* const* d_in, const int* in_sizes, int n_in,
                              void* d_out, int out_size, void* d_ws, size_t ws_size,
                              hipStream_t stream) {
  const float* x      = (const float*)d_in[0];
  const float* wih    = (const float*)d_in[1];
  const float* whh    = (const float*)d_in[2];
  const float* bias   = (const float*)d_in[3];
  const float* bias_n = (const float*)d_in[4];
  const float* wout   = (const float*)d_in[5];
  const float* bout   = (const float*)d_in[6];
  const float* bextra = (const float*)d_in[7];
  float* out = (float*)d_out;

  if (ws_size < WS_NEED) {
    k_dbg<<<4, 256, 0, stream>>>(out, 1.0e6f + (float)(ws_size / 1048576ull));
    return;
  }

  char* ws = (char*)d_ws;
  u32*      wpack = (u32*)(ws + WS_WPACK);
  u32*      prog  = (u32*)(ws + WS_PROG);
  _Float16* igb   = (_Float16*)(ws + WS_IG);
  u32*      pairb = (u32*)(ws + WS_PAIR);

  k_zero<<<16, 256, 0, stream>>>(pairb);
  k_zero_n<<<1, 256, 0, stream>>>(prog, 128);
  k_pack<<<24576, 256, 0, stream>>>(whh, wpack);

  const uint4* wpc = (const uint4*)wpack;
  const _Float16* igc = igb;
  void* kargs[] = {(void*)&wpc, (void*)&igc, (void*)&bias_n, (void*)&pairb,
                   (void*)&x, (void*)&wih, (void*)&bias, (void*)&prog};
  hipLaunchCooperativeKernel(k_fused, dim3(256), dim3(512), kargs, 0, stream);

  k_out<<<250, 256, 0, stream>>>(wout, bout, bextra, pairb, out);
}